// Round 1
// baseline (135.817 us; speedup 1.0000x reference)
//
#include <hip/hip_runtime.h>

// EnsembleGRU fused kernel.
// Shapes: inputs (W=64, E=16, B*I=2560, F=8) f32; out (W, E, B*I, 1) f32.
// Math: gi = W_ih·(W_lin·x + b_lin) + b_ih  folds to  gi = M·x + c  with
//       M[e] = W_ih[e]·W_lin[e]  (3x8),  c[e] = W_ih[e]·b_lin[e] + b_ih[e].
// GRU step (H=1): r=σ(gi0+w0·h+bh0), z=σ(gi1+w1·h+bh1),
//                 n=tanh(gi2 + r·(w2·h+bh2)), h = n + z·(h-n).

namespace {
constexpr int W_T = 64;
constexpr int E_N = 16;
constexpr int B_N = 256;
constexpr int I_N = 10;
constexpr int F_N = 8;
constexpr int PROJ = 16;
constexpr int BI = B_N * I_N;           // 2560
constexpr int WSTRIDE = E_N * BI * F_N; // 327680 floats per timestep
constexpr int OSTRIDE = E_N * BI;       // 40960 floats per timestep
constexpr int NCHAIN = E_N * BI;        // 40960 independent chains
constexpr int BLOCKS_PER_E = BI / 64;   // 40

__device__ __forceinline__ float sigmoid_f(float x) {
    return __frcp_rn(1.f + __expf(-x));
}
__device__ __forceinline__ float tanh_f(float x) {
    // tanh(x) = 1 - 2/(1+exp(2x))
    return __builtin_fmaf(-2.f, __frcp_rn(1.f + __expf(2.f * x)), 1.f);
}
} // namespace

__global__ __launch_bounds__(64, 1) void EnsembleGRUModule_63213328662935_kernel(
    const float* __restrict__ x,    // (W,E,BI,F)
    const float* __restrict__ h0p,  // (1,E,BI,1)
    const float* __restrict__ wl,   // (E,16,8)
    const float* __restrict__ bl,   // (E,16)
    const float* __restrict__ wih,  // (E,3,16)
    const float* __restrict__ whh,  // (E,3,1)
    const float* __restrict__ bih,  // (E,3)
    const float* __restrict__ bhh,  // (E,3)
    float* __restrict__ out)        // (W,E,BI)
{
    const int e = blockIdx.x / BLOCKS_PER_E;            // block-uniform
    const int bi = (blockIdx.x % BLOCKS_PER_E) * 64 + threadIdx.x;
    const int chain = e * BI + bi;

    // ---- fold the two linear layers: M[3][8], c[3] ----
    const float* wl_e = wl + e * (PROJ * F_N);
    const float* wih_e = wih + e * (3 * PROJ);
    float M[3][F_N];
    float c[3];
    #pragma unroll
    for (int g = 0; g < 3; ++g) {
        float cg = bih[e * 3 + g];
        float m[F_N];
        #pragma unroll
        for (int f = 0; f < F_N; ++f) m[f] = 0.f;
        #pragma unroll
        for (int o = 0; o < PROJ; ++o) {
            const float wgo = wih_e[g * PROJ + o];
            cg = __builtin_fmaf(wgo, bl[e * PROJ + o], cg);
            #pragma unroll
            for (int f = 0; f < F_N; ++f)
                m[f] = __builtin_fmaf(wgo, wl_e[o * F_N + f], m[f]);
        }
        #pragma unroll
        for (int f = 0; f < F_N; ++f) M[g][f] = m[f];
        c[g] = cg;
    }
    const float w0 = whh[e * 3 + 0], w1 = whh[e * 3 + 1], w2 = whh[e * 3 + 2];
    // bhh[0]/bhh[1] add linearly to gi0/gi1; bhh[2] multiplies with r -> keep separate
    const float c0 = c[0] + bhh[e * 3 + 0];
    const float c1 = c[1] + bhh[e * 3 + 1];
    const float c2 = c[2];
    const float bh2 = bhh[e * 3 + 2];

    const float* xp = x + (size_t)chain * F_N;
    float* op = out + chain;
    float h = h0p[chain];

    // ---- double-buffered chunks of 8 timesteps; all indices compile-time ----
    constexpr int CH = 8;
    constexpr int NC = W_T / CH;
    float4 buf[2][CH][2];

    #pragma unroll
    for (int j = 0; j < CH; ++j) {
        buf[0][j][0] = *(const float4*)(xp + (size_t)j * WSTRIDE);
        buf[0][j][1] = *(const float4*)(xp + (size_t)j * WSTRIDE + 4);
    }

    #pragma unroll
    for (int chunk = 0; chunk < NC; ++chunk) {
        const int cur = chunk & 1;  // compile-time after full unroll
        if (chunk + 1 < NC) {
            #pragma unroll
            for (int j = 0; j < CH; ++j) {
                const size_t off = (size_t)((chunk + 1) * CH + j) * WSTRIDE;
                buf[cur ^ 1][j][0] = *(const float4*)(xp + off);
                buf[cur ^ 1][j][1] = *(const float4*)(xp + off + 4);
            }
        }
        #pragma unroll
        for (int j = 0; j < CH; ++j) {
            const float4 A = buf[cur][j][0];
            const float4 Bv = buf[cur][j][1];
            const float xv[8] = {A.x, A.y, A.z, A.w, Bv.x, Bv.y, Bv.z, Bv.w};
            float g0 = c0, g1 = c1, g2 = c2;
            #pragma unroll
            for (int f = 0; f < 8; ++f) {
                g0 = __builtin_fmaf(M[0][f], xv[f], g0);
                g1 = __builtin_fmaf(M[1][f], xv[f], g1);
                g2 = __builtin_fmaf(M[2][f], xv[f], g2);
            }
            const float r = sigmoid_f(__builtin_fmaf(w0, h, g0));
            const float z = sigmoid_f(__builtin_fmaf(w1, h, g1));
            const float gh2 = __builtin_fmaf(w2, h, bh2);
            const float n = tanh_f(__builtin_fmaf(r, gh2, g2));
            h = __builtin_fmaf(z, h - n, n);
            op[(size_t)(chunk * CH + j) * OSTRIDE] = h;
        }
    }
}

extern "C" void kernel_launch(void* const* d_in, const int* in_sizes, int n_in,
                              void* d_out, int out_size, void* d_ws, size_t ws_size,
                              hipStream_t stream) {
    const float* x   = (const float*)d_in[0];
    const float* st  = (const float*)d_in[1];
    const float* wl  = (const float*)d_in[2];
    const float* bl  = (const float*)d_in[3];
    const float* wih = (const float*)d_in[4];
    const float* whh = (const float*)d_in[5];
    const float* bih = (const float*)d_in[6];
    const float* bhh = (const float*)d_in[7];
    float* out = (float*)d_out;

    dim3 grid(NCHAIN / 64);
    dim3 block(64);
    hipLaunchKernelGGL(EnsembleGRUModule_63213328662935_kernel, grid, block, 0, stream,
                       x, st, wl, bl, wih, whh, bih, bhh, out);
}